// Round 8
// baseline (176.743 us; speedup 1.0000x reference)
//
#include <hip/hip_runtime.h>
#include <hip/hip_bf16.h>

#define GRID_RES 32
#define GRID_DIM 8
#define N_CELLS  256
#define EMB_VOL  512
#define TAB_N    (GRID_RES * GRID_RES * GRID_RES)   // 32768
#define NPT      2
#define BLOCK    1024

// Sparse trilinear interp + analytic gradient. Branchless, exact fp32.
// BLOCK=1024 so the 64KB LDS table is amortized over 16 waves -> 2 WG/CU
// = 32 waves/CU (100% occupancy) to hide the pos->table->gather chain.
__global__ __launch_bounds__(BLOCK, 8) void neural_poisson_interp(
    const float* __restrict__ positions,   // [N,3]
    const float* __restrict__ embeddings,  // [NUM_EMB, 512]
    const int*   __restrict__ block_table, // [32,32,32]
    float* __restrict__ out,               // emb[N] | grad[N,3] | mask[N]
    int n)
{
    __shared__ short stab[TAB_N];          // 64 KB, int16 block ids
    {
        const int4* t4 = reinterpret_cast<const int4*>(block_table);
        for (int k = threadIdx.x; k < TAB_N / 4; k += BLOCK) {
            int4 v = t4[k];
            short4 s;
            s.x = (short)v.x; s.y = (short)v.y; s.z = (short)v.z; s.w = (short)v.w;
            *reinterpret_cast<short4*>(&stab[4 * k]) = s;
        }
    }
    __syncthreads();

    float* out_emb  = out;
    float* out_grad = out + (size_t)n;
    float* out_mask = out + 4 * (size_t)n;

    int nq = (n + NPT - 1) / NPT;
    int stride = gridDim.x * BLOCK;
    for (int q = blockIdx.x * BLOCK + threadIdx.x; q < nq; q += stride) {
        int i0 = q * NPT;
        bool full = (i0 + NPT <= n);

        float px[NPT], py[NPT], pz[NPT];
        if (full) {
            // 6 floats at 8B-aligned offset: 3x float2
            const float2* p2 = reinterpret_cast<const float2*>(positions + 3 * (size_t)i0);
            float2 A = p2[0], B = p2[1], C = p2[2];
            px[0] = A.x; py[0] = A.y; pz[0] = B.x;
            px[1] = B.y; py[1] = C.x; pz[1] = C.y;
        } else {
#pragma unroll
            for (int p = 0; p < NPT; ++p) {
                int ip = min(i0 + p, n - 1);
                px[p] = positions[3 * ip + 0];
                py[p] = positions[3 * ip + 1];
                pz[p] = positions[3 * ip + 2];
            }
        }

        float wA[NPT][3], wB[NPT][3];
        int bidx[NPT][8];
        int li  [NPT][8];

#pragma unroll
        for (int p = 0; p < NPT; ++p) {
            float xc[3];
            xc[0] = (px[p] + 1.0f) * 0.5f * (float)(N_CELLS - 1);
            xc[1] = (py[p] + 1.0f) * 0.5f * (float)(N_CELLS - 1);
            xc[2] = (pz[p] + 1.0f) * 0.5f * (float)(N_CELLS - 1);
            int base[3];
#pragma unroll
            for (int a = 0; a < 3; ++a) {
                float bf = fminf(fmaxf(floorf(xc[a]), 0.0f), (float)(N_CELLS - 2));
                float fr = xc[a] - bf;
                wA[p][a] = 1.0f - fr;
                wB[p][a] = fr;
                base[a] = (int)bf;
            }
#pragma unroll
            for (int c = 0; c < 8; ++c) {
                int dx = (c >> 2) & 1, dy = (c >> 1) & 1, dz = c & 1;
                int cx = base[0] + dx, cy = base[1] + dy, cz = base[2] + dz;
                bidx[p][c] = stab[((cx >> 3) * GRID_RES + (cy >> 3)) * GRID_RES
                                  + (cz >> 3)];
                li[p][c] = ((cx & 7) * GRID_DIM + (cy & 7)) * GRID_DIM + (cz & 7);
            }
        }

        // all 16 embedding gathers, branchless (clamped index)
        float e[NPT][8];
#pragma unroll
        for (int p = 0; p < NPT; ++p)
#pragma unroll
            for (int c = 0; c < 8; ++c) {
                int b = bidx[p][c] > 0 ? bidx[p][c] : 0;
                e[p][c] = embeddings[b * EMB_VOL + li[p][c]];
            }

        const float scale = 0.5f * (float)(N_CELLS - 1);  // 127.5
        float acc[NPT], gxv[NPT], gyv[NPT], gzv[NPT], mk[NPT];

#pragma unroll
        for (int p = 0; p < NPT; ++p) {
            float a = 0.0f, gx = 0.0f, gy = 0.0f, gz = 0.0f;
            bool vall = true;
#pragma unroll
            for (int c = 0; c < 8; ++c) {
                int dx = (c >> 2) & 1, dy = (c >> 1) & 1, dz = c & 1;
                bool valid = bidx[p][c] >= 0;
                vall = vall && valid;
                float ev = valid ? e[p][c] : 0.0f;
                float wx = dx ? wB[p][0] : wA[p][0];
                float wy = dy ? wB[p][1] : wA[p][1];
                float wz = dz ? wB[p][2] : wA[p][2];
                a += wx * wy * wz * ev;
                float tgx = wy * wz * ev;
                float tgy = wx * wz * ev;
                float tgz = wx * wy * ev;
                gx += dx ? tgx : -tgx;
                gy += dy ? tgy : -tgy;
                gz += dz ? tgz : -tgz;
            }
            acc[p] = a;
            gxv[p] = scale * gx;
            gyv[p] = scale * gy;
            gzv[p] = scale * gz;
            mk[p]  = vall ? 1.0f : 0.0f;
        }

        if (full) {
            *reinterpret_cast<float2*>(out_emb + i0)  = make_float2(acc[0], acc[1]);
            *reinterpret_cast<float2*>(out_mask + i0) = make_float2(mk[0], mk[1]);
            float2* g2 = reinterpret_cast<float2*>(out_grad + 3 * (size_t)i0);
            g2[0] = make_float2(gxv[0], gyv[0]);
            g2[1] = make_float2(gzv[0], gxv[1]);
            g2[2] = make_float2(gyv[1], gzv[1]);
        } else {
#pragma unroll
            for (int p = 0; p < NPT; ++p) {
                int ip = i0 + p;
                if (ip < n) {
                    out_emb[ip]          = acc[p];
                    out_grad[3 * ip + 0] = gxv[p];
                    out_grad[3 * ip + 1] = gyv[p];
                    out_grad[3 * ip + 2] = gzv[p];
                    out_mask[ip]         = mk[p];
                }
            }
        }
    }
}

extern "C" void kernel_launch(void* const* d_in, const int* in_sizes, int n_in,
                              void* d_out, int out_size, void* d_ws, size_t ws_size,
                              hipStream_t stream) {
    const float* positions   = (const float*)d_in[0];
    const float* embeddings  = (const float*)d_in[1];
    const int*   block_table = (const int*)d_in[2];

    int n = in_sizes[0] / 3;
    int nq = (n + NPT - 1) / NPT;

    float* out = (float*)d_out;

    int grid = 512;                           // persistent: 2 WGs/CU
    int maxg = (nq + BLOCK - 1) / BLOCK;
    if (grid > maxg) grid = maxg;
    neural_poisson_interp<<<grid, BLOCK, 0, stream>>>(
        positions, embeddings, block_table, out, n);
}

// Round 10
// 129.167 us; speedup vs baseline: 1.3683x; 1.3683x over previous
//
#include <hip/hip_runtime.h>
#include <hip/hip_bf16.h>

#define GRID_RES 32
#define GRID_DIM 8
#define N_CELLS  256
#define EMB_VOL  512
#define TAB_N    (GRID_RES * GRID_RES * GRID_RES)   // 32768
#define NPT      4
#define BLOCK    512

// Sparse trilinear interp + analytic gradient, exact fp32.
// R5 structure (LDS int16 table, 512 thr, 4 pts/thread, float4 stores) with
// z-pair gathers: each (dx,dy) corner pair = ONE aligned float4 load covering
// lz..lz+1 (plus a rare exec-masked scalar load when (lz&3)==3, 25% of lanes,
// which also handles the z block-crossing). 8 -> ~5 TA lookups per point.
__global__ __launch_bounds__(BLOCK) void neural_poisson_interp(
    const float* __restrict__ positions,   // [N,3]
    const float* __restrict__ embeddings,  // [NUM_EMB, 512]
    const int*   __restrict__ block_table, // [32,32,32]
    float* __restrict__ out,               // emb[N] | grad[N,3] | mask[N]
    int n)
{
    __shared__ short stab[TAB_N];          // 64 KB, int16 block ids
    {
        const int4* t4 = reinterpret_cast<const int4*>(block_table);
        for (int k = threadIdx.x; k < TAB_N / 4; k += BLOCK) {
            int4 v = t4[k];
            short4 s;
            s.x = (short)v.x; s.y = (short)v.y; s.z = (short)v.z; s.w = (short)v.w;
            *reinterpret_cast<short4*>(&stab[4 * k]) = s;
        }
    }
    __syncthreads();

    const float4* emb4 = reinterpret_cast<const float4*>(embeddings);
    float* out_emb  = out;
    float* out_grad = out + (size_t)n;
    float* out_mask = out + 4 * (size_t)n;

    int nq = (n + NPT - 1) / NPT;
    int stride = gridDim.x * BLOCK;
    for (int q = blockIdx.x * BLOCK + threadIdx.x; q < nq; q += stride) {
        int i0 = q * NPT;
        bool full = (i0 + NPT <= n);

        float px[NPT], py[NPT], pz[NPT];
        if (full) {
            const float4* p4 = reinterpret_cast<const float4*>(positions + 3 * (size_t)i0);
            float4 A = p4[0], B = p4[1], C = p4[2];
            px[0]=A.x; py[0]=A.y; pz[0]=A.z;
            px[1]=A.w; py[1]=B.x; pz[1]=B.y;
            px[2]=B.z; py[2]=B.w; pz[2]=C.x;
            px[3]=C.y; py[3]=C.z; pz[3]=C.w;
        } else {
#pragma unroll
            for (int p = 0; p < NPT; ++p) {
                int ip = min(i0 + p, n - 1);
                px[p] = positions[3 * ip + 0];
                py[p] = positions[3 * ip + 1];
                pz[p] = positions[3 * ip + 2];
            }
        }

        float wA[NPT][3], wB[NPT][3];
        int tpk [NPT][4];   // packed (t0 | t1<<16) per (dx,dy) pair
        int off0[NPT][4];   // element offset of dz=0 corner within block

#pragma unroll
        for (int p = 0; p < NPT; ++p) {
            float xc[3];
            xc[0] = (px[p] + 1.0f) * 0.5f * (float)(N_CELLS - 1);
            xc[1] = (py[p] + 1.0f) * 0.5f * (float)(N_CELLS - 1);
            xc[2] = (pz[p] + 1.0f) * 0.5f * (float)(N_CELLS - 1);
            int base[3];
#pragma unroll
            for (int a = 0; a < 3; ++a) {
                float bf = fminf(fmaxf(floorf(xc[a]), 0.0f), (float)(N_CELLS - 2));
                float fr = xc[a] - bf;
                wA[p][a] = 1.0f - fr;
                wB[p][a] = fr;
                base[a] = (int)bf;
            }
            int bx = base[0], by = base[1], bz = base[2];
            int lz = bz & 7;
            int eidx = ((bx >> 3) * GRID_RES + (by >> 3)) * GRID_RES + (bz >> 3);
            int ox = ((bx & 7) == 7) ? (GRID_RES * GRID_RES) : 0;
            int oy = ((by & 7) == 7) ? GRID_RES : 0;
            int oz = ((bz & 7) == 7) ? 1 : 0;
#pragma unroll
            for (int i = 0; i < 4; ++i) {
                int dx = i >> 1, dy = i & 1;
                int e0i = eidx + (dx ? ox : 0) + (dy ? oy : 0);
                int t0 = stab[e0i];
                int t1 = stab[e0i + oz];
                tpk[p][i] = (t0 & 0xffff) | (t1 << 16);
                int row = (((bx + dx) & 7) * 8 + ((by + dy) & 7));
                off0[p][i] = row * 8 + lz;
            }
        }

        // gathers: one aligned float4 per pair; masked scalar when sel==3
        float ee0[NPT][4], ee1[NPT][4];
#pragma unroll
        for (int p = 0; p < NPT; ++p)
#pragma unroll
            for (int i = 0; i < 4; ++i) {
                int t0 = (short)(tpk[p][i] & 0xffff);
                int t1 = tpk[p][i] >> 16;
                int b0 = t0 > 0 ? t0 : 0;
                int o  = off0[p][i];
                int sel = o & 3;
                float4 f = emb4[(size_t)b0 * (EMB_VOL / 4) + (o >> 2)];
                float e0 = sel == 0 ? f.x : sel == 1 ? f.y : sel == 2 ? f.z : f.w;
                float e1 = sel == 0 ? f.y : sel == 1 ? f.z : f.w;
                if (sel == 3) {          // lz in {3,7}: next float4 or next block
                    int lz7 = (o & 7) == 7;
                    int bb  = lz7 ? (t1 > 0 ? t1 : 0) : b0;
                    int oo  = lz7 ? (o & ~7) : (o + 1);
                    e1 = embeddings[(size_t)bb * EMB_VOL + oo];
                }
                ee0[p][i] = t0 >= 0 ? e0 : 0.0f;
                ee1[p][i] = t1 >= 0 ? e1 : 0.0f;
            }

        const float scale = 0.5f * (float)(N_CELLS - 1);  // 127.5
        float acc[NPT], gxv[NPT], gyv[NPT], gzv[NPT], mk[NPT];

#pragma unroll
        for (int p = 0; p < NPT; ++p) {
            float wz0 = wA[p][2], wz1 = wB[p][2];
            float a = 0.0f, gx = 0.0f, gy = 0.0f, gz = 0.0f;
            int sgn = -1;   // all-ones; AND sign bits of all 8 table values
#pragma unroll
            for (int i = 0; i < 4; ++i) {
                int t0 = (short)(tpk[p][i] & 0xffff);
                int t1 = tpk[p][i] >> 16;
                sgn &= t0 & t1;
                int dx = i >> 1, dy = i & 1;
                float e0 = ee0[p][i], e1 = ee1[p][i];
                float s = wz0 * e0 + wz1 * e1;
                float wx = dx ? wB[p][0] : wA[p][0];
                float wy = dy ? wB[p][1] : wA[p][1];
                float wxy = wx * wy;
                a  += wxy * s;
                gx += dx ? wy * s : -wy * s;
                gy += dy ? wx * s : -wx * s;
                gz += wxy * (e1 - e0);
            }
            acc[p] = a;
            gxv[p] = scale * gx;
            gyv[p] = scale * gy;
            gzv[p] = scale * gz;
            mk[p]  = (sgn >= 0) ? 1.0f : 0.0f;
        }

        if (full) {
            *reinterpret_cast<float4*>(out_emb + i0) =
                make_float4(acc[0], acc[1], acc[2], acc[3]);
            float4* g4 = reinterpret_cast<float4*>(out_grad + 3 * (size_t)i0);
            g4[0] = make_float4(gxv[0], gyv[0], gzv[0], gxv[1]);
            g4[1] = make_float4(gyv[1], gzv[1], gxv[2], gyv[2]);
            g4[2] = make_float4(gzv[2], gxv[3], gyv[3], gzv[3]);
            *reinterpret_cast<float4*>(out_mask + i0) =
                make_float4(mk[0], mk[1], mk[2], mk[3]);
        } else {
#pragma unroll
            for (int p = 0; p < NPT; ++p) {
                int ip = i0 + p;
                if (ip < n) {
                    out_emb[ip]          = acc[p];
                    out_grad[3 * ip + 0] = gxv[p];
                    out_grad[3 * ip + 1] = gyv[p];
                    out_grad[3 * ip + 2] = gzv[p];
                    out_mask[ip]         = mk[p];
                }
            }
        }
    }
}

extern "C" void kernel_launch(void* const* d_in, const int* in_sizes, int n_in,
                              void* d_out, int out_size, void* d_ws, size_t ws_size,
                              hipStream_t stream) {
    const float* positions   = (const float*)d_in[0];
    const float* embeddings  = (const float*)d_in[1];
    const int*   block_table = (const int*)d_in[2];

    int n = in_sizes[0] / 3;
    int nq = (n + NPT - 1) / NPT;

    float* out = (float*)d_out;

    int grid = 512;                           // persistent: 2 WGs/CU
    int maxg = (nq + BLOCK - 1) / BLOCK;
    if (grid > maxg) grid = maxg;
    neural_poisson_interp<<<grid, BLOCK, 0, stream>>>(
        positions, embeddings, block_table, out, n);
}